// Round 3
// baseline (1048.065 us; speedup 1.0000x reference)
//
#include <hip/hip_runtime.h>
#include <hip/hip_cooperative_groups.h>
namespace cg = cooperative_groups;

typedef __bf16 bf16x8 __attribute__((ext_vector_type(8)));
typedef float f32x4 __attribute__((ext_vector_type(4)));
typedef unsigned short u16x8 __attribute__((ext_vector_type(8)));

#define FIN 512
#define FOUT 256
#define NBLK 256          // blocks for the cooperative CSR kernel
#define BSHIFT 8          // bucket = 256 consecutive src nodes

__device__ __forceinline__ float b2f(unsigned short u) {
  union { unsigned int u; float f; } x;
  x.u = ((unsigned int)u) << 16;
  return x.f;
}
__device__ __forceinline__ unsigned short f2b(float f) {
  union { float f; unsigned int u; } x; x.f = f;
  unsigned int u = x.u;
  unsigned int r = (u + 0x7fffu + ((u >> 16) & 1u)) >> 16;
  return (unsigned short)r;
}
// packed f32->bf16 (RNE), 2 values -> 1 dword. gfx950 has no builtin; inline asm.
__device__ __forceinline__ unsigned int cvt_pk_bf16(float lo, float hi) {
  unsigned int r;
  asm("v_cvt_pk_bf16_f32 %0, %1, %2" : "=v"(r) : "v"(lo), "v"(hi));
  return r;
}

// ==================== cooperative fused pre+CSR kernel ====================
// Phases (grid.sync between): A probe (block 0) -> B W-transpose + bucket
// histogram -> C per-bucket scan over block counts -> D bucket-total scan
// (block 0) -> E bucket-grouped scatter -> F per-bucket fine sort.
// 256 blocks x 256 threads, 3KB LDS -> trivially co-resident.
__global__ __launch_bounds__(256) void k_csr_all(
    const unsigned short* __restrict__ xh, const int* __restrict__ e,
    int* __restrict__ flags, const void* __restrict__ W,
    unsigned short* __restrict__ Wt, int E, int chunk, int nbuck,
    int* __restrict__ C, int* __restrict__ O, int* __restrict__ btot,
    int* __restrict__ bbase, int* __restrict__ rowptr,
    int* __restrict__ stage, int* __restrict__ csrd, int N) {
  cg::grid_group grid = cg::this_grid();
  __shared__ int shm[768];
  const int t = threadIdx.x;
  const int blk = blockIdx.x;

  // ---- phase A: dtype probe. flags[0]=X is fp32; flags[1]=edge is int64.
  if (blk == 0) {
    if (t == 0) { shm[0] = 0; shm[1] = 0; }
    __syncthreads();
    int c = 0;
    for (int i = t; i < 32768; i += 256) {
      unsigned short u = xh[i];
      if (((u >> 7) & 0xFF) == 0xFF) c++;
    }
    if (c) atomicAdd(&shm[0], c);
    if (e[2 * t + 1] == 0) atomicAdd(&shm[1], 1);
    __syncthreads();
    if (t == 0) {
      flags[0] = (shm[0] > 0) ? 1 : 0;
      flags[1] = (shm[1] > 128) ? 1 : 0;
    }
  }
  __threadfence();
  grid.sync();

  const int isf = flags[0];
  const bool i64 = flags[1] != 0;

  // ---- phase B: W transpose (Wt[n*512+k] = bf16(W[k*256+n])) + histogram.
#pragma unroll
  for (int k2 = 0; k2 < 2; k2++) {
    int idx = blk * 512 + k2 * 256 + t;
    int kk = idx >> 8, nn = idx & 255;
    float v = isf ? ((const float*)W)[idx]
                  : b2f(((const unsigned short*)W)[idx]);
    Wt[nn * FIN + kk] = f2b(v);
  }
  for (int i = t; i < nbuck; i += 256) shm[i] = 0;
  __syncthreads();
  {
    int lo = blk * chunk, hi = min(E, lo + chunk);
    for (int i = lo + t; i < hi; i += 256) {
      int s = i64 ? ((const int2*)e)[i].x : e[i];
      atomicAdd(&shm[s >> BSHIFT], 1);
    }
  }
  __syncthreads();
  for (int i = t; i < nbuck; i += 256) C[blk * nbuck + i] = shm[i];
  __threadfence();
  grid.sync();

  // ---- phase C: per-bucket exclusive scan over the 256 block counts.
  for (int k2 = 0; k2 < 2; k2++) {
    __syncthreads();
    int b = blk + k2 * 256;
    if (b < nbuck) {
      int lane = t & 63, w = t >> 6;
      int v = C[t * nbuck + b];
      int x = v;
#pragma unroll
      for (int off = 1; off < 64; off <<= 1) {
        int y = __shfl_up(x, off, 64);
        if (lane >= off) x += y;
      }
      if (lane == 63) shm[512 + w] = x;
      __syncthreads();
      int wbase = (w > 0 ? shm[512] : 0) + (w > 1 ? shm[513] : 0) + (w > 2 ? shm[514] : 0);
      O[t * nbuck + b] = x + wbase - v;
      if (t == 255) btot[b] = x + wbase;
    }
  }
  __threadfence();
  grid.sync();

  // ---- phase D: scan of bucket totals -> bbase[0..nbuck], rowptr[N]=E (block 0).
  if (blk == 0) {
    int v0 = (t < nbuck) ? btot[t] : 0;
    int v1 = (t + 256 < nbuck) ? btot[t + 256] : 0;
    shm[t] = v0; shm[t + 256] = v1;
    __syncthreads();
    for (int off = 1; off < 512; off <<= 1) {
      int a0 = (t >= off) ? shm[t - off] : 0;
      int a1 = (t + 256 >= off) ? shm[t + 256 - off] : 0;
      __syncthreads();
      shm[t] += a0; shm[t + 256] += a1;
      __syncthreads();
    }
    if (t < nbuck) bbase[t] = shm[t] - v0;
    if (t + 256 < nbuck) bbase[t + 256] = shm[t + 256] - v1;
    if (t == nbuck - 1) { bbase[nbuck] = shm[t]; rowptr[N] = shm[t]; }
    if (t + 256 == nbuck - 1) { bbase[nbuck] = shm[t + 256]; rowptr[N] = shm[t + 256]; }
  }
  __threadfence();
  grid.sync();

  // ---- phase E: scatter packed (slocal<<17)|dst into bucket-grouped stage.
  for (int i = t; i < nbuck; i += 256) shm[i] = bbase[i] + O[blk * nbuck + i];
  __syncthreads();
  {
    int lo = blk * chunk, hi = min(E, lo + chunk);
    for (int i = lo + t; i < hi; i += 256) {
      int s, d;
      if (i64) { s = ((const int2*)e)[i].x; d = ((const int2*)e)[(size_t)E + i].x; }
      else     { s = e[i];                  d = e[E + i]; }
      int pos = atomicAdd(&shm[s >> BSHIFT], 1);
      stage[pos] = ((s & 255) << 17) | d;
    }
  }
  __threadfence();
  grid.sync();

  // ---- phase F: per-bucket fine counting sort -> rowptr slice + csrd.
  for (int k2 = 0; k2 < 2; k2++) {
    __syncthreads();
    int b = blk + k2 * 256;
    if (b >= nbuck) continue;
    int s0 = b << BSHIFT;
    int base = bbase[b], end2 = bbase[b + 1], cnt = end2 - base;
    int* hist = shm;          // [256]
    int* cursor = shm + 256;  // [256]
    int* ws = shm + 512;      // [4]
    hist[t] = 0;
    __syncthreads();
    for (int i = t; i < cnt; i += 256) atomicAdd(&hist[stage[base + i] >> 17], 1);
    __syncthreads();
    int v = hist[t];
    int lane = t & 63, w = t >> 6;
    int x = v;
#pragma unroll
    for (int off = 1; off < 64; off <<= 1) {
      int y = __shfl_up(x, off, 64);
      if (lane >= off) x += y;
    }
    if (lane == 63) ws[w] = x;
    __syncthreads();
    int wbase = (w > 0 ? ws[0] : 0) + (w > 1 ? ws[1] : 0) + (w > 2 ? ws[2] : 0);
    int excl = x + wbase - v;
    cursor[t] = base + excl;
    if (s0 + t < N) rowptr[s0 + t] = base + excl;
    __syncthreads();
    for (int i = t; i < cnt; i += 256) {
      int p = stage[base + i];
      int pos = atomicAdd(&cursor[p >> 17], 1);
      csrd[pos] = p & 0x1FFFF;
    }
  }
}

// ==================== legacy (fallback) pre+CSR kernels ====================
__global__ void k_probe(const unsigned short* __restrict__ xh,
                        const int* __restrict__ e, int* __restrict__ flags) {
  __shared__ int cnt[2];
  if (threadIdx.x == 0) { cnt[0] = 0; cnt[1] = 0; }
  __syncthreads();
  int c = 0;
  for (int i = threadIdx.x; i < 32768; i += 256) {
    unsigned short u = xh[i];
    if (((u >> 7) & 0xFF) == 0xFF) c++;
  }
  if (c) atomicAdd(&cnt[0], c);
  if (e[2 * threadIdx.x + 1] == 0) atomicAdd(&cnt[1], 1);
  __syncthreads();
  if (threadIdx.x == 0) {
    flags[0] = (cnt[0] > 0) ? 1 : 0;
    flags[1] = (cnt[1] > 128) ? 1 : 0;
  }
}

__global__ void k_transpose(const void* __restrict__ W,
                            unsigned short* __restrict__ Wt,
                            const int* __restrict__ flags) {
  int idx = blockIdx.x * 256 + threadIdx.x;
  int k = idx >> 8, n = idx & 255;
  float v = flags[0] ? ((const float*)W)[idx]
                     : b2f(((const unsigned short*)W)[idx]);
  Wt[n * FIN + k] = f2b(v);
}

__global__ __launch_bounds__(256) void k_bcount(const int* __restrict__ e, int E, int chunk,
                                                int nbuck, int* __restrict__ C,
                                                const int* __restrict__ flags) {
  __shared__ int hist[512];
  int t = threadIdx.x, blk = blockIdx.x;
  for (int i = t; i < nbuck; i += 256) hist[i] = 0;
  __syncthreads();
  int lo = blk * chunk, hi = min(E, lo + chunk);
  bool i64 = flags[1] != 0;
  for (int i = lo + t; i < hi; i += 256) {
    int s = i64 ? ((const int2*)e)[i].x : e[i];
    atomicAdd(&hist[s >> BSHIFT], 1);
  }
  __syncthreads();
  for (int i = t; i < nbuck; i += 256) C[blk * nbuck + i] = hist[i];
}

__global__ __launch_bounds__(256) void k_bscanA(const int* __restrict__ C, int nbuck,
                                                int* __restrict__ O, int* __restrict__ btot) {
  int b = blockIdx.x, t = threadIdx.x;
  int lane = t & 63, w = t >> 6;
  int v = C[t * nbuck + b];
  int x = v;
#pragma unroll
  for (int off = 1; off < 64; off <<= 1) {
    int y = __shfl_up(x, off, 64);
    if (lane >= off) x += y;
  }
  __shared__ int ws[4];
  if (lane == 63) ws[w] = x;
  __syncthreads();
  int wbase = (w > 0 ? ws[0] : 0) + (w > 1 ? ws[1] : 0) + (w > 2 ? ws[2] : 0);
  O[t * nbuck + b] = x + wbase - v;
  if (t == 255) btot[b] = x + wbase;
}

__global__ __launch_bounds__(512) void k_bscanB(const int* __restrict__ btot, int nbuck,
                                                int* __restrict__ bbase,
                                                int* __restrict__ rowptr, int N) {
  __shared__ int sh[512];
  int t = threadIdx.x;
  int v = (t < nbuck) ? btot[t] : 0;
  sh[t] = v;
  __syncthreads();
  for (int off = 1; off < 512; off <<= 1) {
    int u = (t >= off) ? sh[t - off] : 0;
    __syncthreads();
    sh[t] += u;
    __syncthreads();
  }
  if (t < nbuck) bbase[t] = sh[t] - v;
  if (t == nbuck - 1) { bbase[nbuck] = sh[t]; rowptr[N] = sh[t]; }
}

__global__ __launch_bounds__(256) void k_bscatter(const int* __restrict__ e, int E, int chunk,
                                                  int nbuck, const int* __restrict__ O,
                                                  const int* __restrict__ bbase,
                                                  int* __restrict__ stage,
                                                  const int* __restrict__ flags) {
  __shared__ int cur[512];
  int t = threadIdx.x, blk = blockIdx.x;
  for (int i = t; i < nbuck; i += 256) cur[i] = bbase[i] + O[blk * nbuck + i];
  __syncthreads();
  int lo = blk * chunk, hi = min(E, lo + chunk);
  bool i64 = flags[1] != 0;
  for (int i = lo + t; i < hi; i += 256) {
    int s, d;
    if (i64) { s = ((const int2*)e)[i].x; d = ((const int2*)e)[(size_t)E + i].x; }
    else     { s = e[i];                  d = e[E + i]; }
    int pos = atomicAdd(&cur[s >> BSHIFT], 1);
    stage[pos] = ((s & 255) << 17) | d;
  }
}

__global__ __launch_bounds__(256) void k_fine(const int* __restrict__ stage,
                                              const int* __restrict__ bbase,
                                              int* __restrict__ rowptr,
                                              int* __restrict__ csrd, int N) {
  __shared__ int hist[256];
  __shared__ int cursor[256];
  __shared__ int ws[4];
  int b = blockIdx.x, t = threadIdx.x;
  int s0 = b << BSHIFT;
  int base = bbase[b], end = bbase[b + 1], cnt = end - base;
  hist[t] = 0;
  __syncthreads();
  for (int i = t; i < cnt; i += 256) atomicAdd(&hist[stage[base + i] >> 17], 1);
  __syncthreads();
  int v = hist[t];
  int lane = t & 63, w = t >> 6;
  int x = v;
#pragma unroll
  for (int off = 1; off < 64; off <<= 1) {
    int y = __shfl_up(x, off, 64);
    if (lane >= off) x += y;
  }
  if (lane == 63) ws[w] = x;
  __syncthreads();
  int wbase = (w > 0 ? ws[0] : 0) + (w > 1 ? ws[1] : 0) + (w > 2 ? ws[2] : 0);
  int excl = x + wbase - v;
  cursor[t] = base + excl;
  if (s0 + t < N) rowptr[s0 + t] = base + excl;
  __syncthreads();
  for (int i = t; i < cnt; i += 256) {
    int p = stage[base + i];
    int pos = atomicAdd(&cursor[p >> 17], 1);
    csrd[pos] = p & 0x1FFFF;
  }
}

// ==================== GEMM (+fused scores) ====================
__global__ __launch_bounds__(256) void k_gemm(const void* __restrict__ X,
                                              const unsigned short* __restrict__ Wt,
                                              const void* __restrict__ bias,
                                              const void* __restrict__ A,
                                              unsigned short* __restrict__ H,
                                              float* __restrict__ s1,
                                              float* __restrict__ s2,
                                              int nrows, const int* __restrict__ flags) {
  __shared__ char lds[65536];
  const int tid = threadIdx.x;
  const int wave = tid >> 6;
  const int lane = tid & 63;
  const int fm = lane & 15;
  const int fq = lane >> 4;
  const int isf = flags[0];
  const int m0 = blockIdx.x * 64;

  if (isf) {
#pragma unroll 4
    for (int j = 0; j < 16; ++j) {
      int r = wave * 16 + j;
      int grow = m0 + r; if (grow >= nrows) grow = nrows - 1;
      int c = lane ^ (j & 7);
      const float* gp = (const float*)X + (size_t)grow * FIN + c * 8;
      f32x4 lo = *(const f32x4*)gp;
      f32x4 hi = *(const f32x4*)(gp + 4);
      uint4 pk;
      pk.x = cvt_pk_bf16(lo[0], lo[1]);
      pk.y = cvt_pk_bf16(lo[2], lo[3]);
      pk.z = cvt_pk_bf16(hi[0], hi[1]);
      pk.w = cvt_pk_bf16(hi[2], hi[3]);
      *(uint4*)(lds + r * 1024 + lane * 16) = pk;
    }
  } else {
#pragma unroll
    for (int j = 0; j < 16; ++j) {
      int r = wave * 16 + j;
      int grow = m0 + r; if (grow >= nrows) grow = nrows - 1;
      int c = lane ^ (j & 7);
      const unsigned short* gp = (const unsigned short*)X + (size_t)grow * FIN + c * 8;
      __builtin_amdgcn_global_load_lds(
          (const __attribute__((address_space(1))) void*)gp,
          (__attribute__((address_space(3))) void*)(lds + r * 1024), 16, 0, 0);
    }
  }
  __syncthreads();

  f32x4 acc[4][4];
#pragma unroll
  for (int i = 0; i < 4; i++)
#pragma unroll
    for (int j = 0; j < 4; j++) acc[i][j] = (f32x4){0.f, 0.f, 0.f, 0.f};

  const unsigned short* wp[4];
#pragma unroll
  for (int i = 0; i < 4; i++)
    wp[i] = Wt + (size_t)((wave * 4 + i) * 16 + fm) * FIN + fq * 8;

  const int swz = fm & 7;
  bf16x8 bcur[4];
#pragma unroll
  for (int i = 0; i < 4; i++) bcur[i] = *(const bf16x8*)(wp[i]);

  for (int it = 0; it < 16; ++it) {
    int itn = (it + 1 < 16) ? it + 1 : 15;
    bf16x8 bnext[4];
#pragma unroll
    for (int i = 0; i < 4; i++) bnext[i] = *(const bf16x8*)(wp[i] + itn * 32);
    bf16x8 af[4];
#pragma unroll
    for (int mt = 0; mt < 4; mt++) {
      int slot = (it * 4 + fq) ^ swz;
      af[mt] = *(const bf16x8*)(lds + (mt * 16 + fm) * 1024 + slot * 16);
    }
#pragma unroll
    for (int mt = 0; mt < 4; mt++)
#pragma unroll
      for (int i = 0; i < 4; i++)
        acc[mt][i] = __builtin_amdgcn_mfma_f32_16x16x32_bf16(af[mt], bcur[i], acc[mt][i], 0, 0, 0);
#pragma unroll
    for (int i = 0; i < 4; i++) bcur[i] = bnext[i];
  }

  // ---- epilogue: H store + fused score partials.
  __syncthreads();               // done with A-tile LDS; reuse for score reduce
  float* sc1 = (float*)lds;      // [4 waves][64 rows]
  float* sc2 = sc1 + 256;

  float bvv[4], asv[4], adv[4];
#pragma unroll
  for (int i = 0; i < 4; i++) {
    int col = (wave * 4 + i) * 16 + fm;
    if (isf) {
      bvv[i] = ((const float*)bias)[col];
      asv[i] = ((const float*)A)[col];
      adv[i] = ((const float*)A)[FOUT + col];
    } else {
      bvv[i] = b2f(((const unsigned short*)bias)[col]);
      asv[i] = b2f(((const unsigned short*)A)[col]);
      adv[i] = b2f(((const unsigned short*)A)[FOUT + col]);
    }
  }

#pragma unroll
  for (int mt = 0; mt < 4; mt++) {
#pragma unroll
    for (int r = 0; r < 4; r++) {
      int row = m0 + mt * 16 + fq * 4 + r;
      float p1 = 0.f, p2 = 0.f;
#pragma unroll
      for (int i = 0; i < 4; i++) {
        float h = acc[mt][i][r] + bvv[i];
        if (row < nrows) H[(size_t)row * FOUT + (wave * 4 + i) * 16 + fm] = f2b(h);
        p1 += h * asv[i];
        p2 += h * adv[i];
      }
#pragma unroll
      for (int off = 1; off < 16; off <<= 1) {
        p1 += __shfl_xor(p1, off, 64);
        p2 += __shfl_xor(p2, off, 64);
      }
      if (fm == 0) {
        int rl = mt * 16 + fq * 4 + r;
        sc1[wave * 64 + rl] = p1;
        sc2[wave * 64 + rl] = p2;
      }
    }
  }
  __syncthreads();
  if (tid < 64) {
    int row = m0 + tid;
    if (row < nrows) {
      s1[row] = sc1[tid] + sc1[64 + tid] + sc1[128 + tid] + sc1[192 + tid];
      s2[row] = sc2[tid] + sc2[64 + tid] + sc2[128 + tid] + sc2[192 + tid];
    }
  }
}

// ==================== gather (row-range version) ====================
// Per 64-edge chunk, preload (dst, s2[dst]) into a per-wave LDS buffer, then
// inner loop = {broadcast ds_read_b64 + independent 16B H load + FMA}.
// Launched 4x on row ranges so other dispatches become visible in top-5.
__global__ __launch_bounds__(256) void k_gather(const unsigned short* __restrict__ H,
                                                const float* __restrict__ s1,
                                                const float* __restrict__ s2,
                                                const int* __restrict__ rowptr,
                                                const int* __restrict__ csrd,
                                                void* __restrict__ out, int row0, int n,
                                                const int* __restrict__ flags) {
  __shared__ int2 eds[4][64];
  int wave = threadIdx.x >> 6, lane = threadIdx.x & 63;
  int row = row0 + blockIdx.x * 4 + wave;
  if (row >= n) return;
  int half = lane >> 5;
  int hl = lane & 31;
  int beg = rowptr[row], end = rowptr[row + 1];
  float s1v = s1[row];
  const unsigned short* Hb = H + hl * 8;   // per-lane column base; row offset is d*FOUT
  float ac[8];
#pragma unroll
  for (int k = 0; k < 8; k++) ac[k] = 0.f;
  float wsum = 0.f;

  for (int base = beg; base < end; base += 64) {
    int cnt = end - base; if (cnt > 64) cnt = 64;
    int d_pre = 0;
    float s_pre = -1e30f;                  // exp -> 0 for pad slots
    if (lane < cnt) { d_pre = csrd[base + lane]; s_pre = s2[d_pre]; }
    eds[wave][lane] = make_int2(d_pre, __float_as_int(s_pre));  // all 64 lanes write

#pragma unroll 8
    for (int j = 0; j < cnt; j += 2) {
      int jj = j + half;                   // uniform per half-wave -> LDS broadcast
      int2 p = eds[wave][jj];
      int dd = p.x;
      float v = s1v + __int_as_float(p.y);
      v = v > 0.f ? v : 0.2f * v;
      float w = (jj < cnt) ? __expf(v) : 0.f;
      union { u16x8 v; unsigned short u[8]; } hv;
      hv.v = *(const u16x8*)(Hb + (size_t)dd * FOUT);
      wsum += w;
#pragma unroll
      for (int k = 0; k < 8; k++) ac[k] += w * b2f(hv.u[k]);
    }
  }

#pragma unroll
  for (int k = 0; k < 8; k++) ac[k] += __shfl_down(ac[k], 32, 64);
  wsum += __shfl_down(wsum, 32, 64);

  if (half == 0) {
    float inv = 1.f / (wsum + 9e-15f);
    float o[8];
#pragma unroll
    for (int k = 0; k < 8; k++) {
      float x = ac[k] * inv;
      o[k] = x > 0.f ? x : __expf(x) - 1.f;
    }
    if (flags[0]) {
      float* op = (float*)out + (size_t)row * FOUT + hl * 8;
      *(f32x4*)op = (f32x4){o[0], o[1], o[2], o[3]};
      *(f32x4*)(op + 4) = (f32x4){o[4], o[5], o[6], o[7]};
    } else {
      union { u16x8 v; unsigned short u[8]; } ov;
#pragma unroll
      for (int k = 0; k < 8; k++) ov.u[k] = f2b(o[k]);
      *(u16x8*)((unsigned short*)out + (size_t)row * FOUT + hl * 8) = ov.v;
    }
  }
}

extern "C" void kernel_launch(void* const* d_in, const int* in_sizes, int n_in,
                              void* d_out, int out_size, void* d_ws, size_t ws_size,
                              hipStream_t stream) {
  const void* X = d_in[0];
  const int* edge = (const int*)d_in[1];
  const void* W = d_in[2];
  const void* A = d_in[3];
  const void* B = d_in[4];
  int N_ = in_sizes[0] / FIN;     // 100000
  int E_ = in_sizes[1] / 2;       // 3200000
  int nbuck = (N_ + 255) >> BSHIFT;        // 391
  int chunk = (E_ + NBLK - 1) / NBLK;      // 12500

  char* p = (char*)d_ws;
  auto alloc = [&](size_t bytes) {
    char* r = p; p += (bytes + 255) & ~(size_t)255; return r;
  };
  int* flags = (int*)alloc(256);
  unsigned short* H  = (unsigned short*)alloc((size_t)N_ * FOUT * 2);
  unsigned short* Wt = (unsigned short*)alloc((size_t)FIN * FOUT * 2);
  float* s1   = (float*)alloc((size_t)N_ * 4);
  float* s2   = (float*)alloc((size_t)N_ * 4);
  int* rowptr = (int*)alloc((size_t)(N_ + 1) * 4);
  int* csrd   = (int*)alloc((size_t)E_ * 4);
  int* C      = (int*)alloc((size_t)NBLK * nbuck * 4);
  int* O      = (int*)alloc((size_t)NBLK * nbuck * 4);
  int* btot   = (int*)alloc((size_t)nbuck * 4);
  int* bbase  = (int*)alloc((size_t)(nbuck + 1) * 4);
  int* stage  = (int*)alloc((size_t)E_ * 4);

  // ---- fused cooperative pre+CSR (with non-cooperative fallback)
  {
    const unsigned short* xh_ = (const unsigned short*)X;
    const int* e_ = edge;
    int* flags_ = flags;
    const void* W_ = W;
    unsigned short* Wt_ = Wt;
    int E2 = E_, chunk2 = chunk, nbuck2 = nbuck, N2 = N_;
    int* C_ = C; int* O_ = O; int* btot_ = btot; int* bbase_ = bbase;
    int* rowptr_ = rowptr; int* stage_ = stage; int* csrd_ = csrd;
    void* cargs[] = {&xh_, &e_, &flags_, &W_, &Wt_, &E2, &chunk2, &nbuck2,
                     &C_, &O_, &btot_, &bbase_, &rowptr_, &stage_, &csrd_, &N2};
    hipError_t cerr = hipLaunchCooperativeKernel((const void*)k_csr_all,
                        dim3(NBLK), dim3(256), cargs, 0, stream);
    if (cerr != hipSuccess) {
      k_probe<<<1, 256, 0, stream>>>(xh_, edge, flags);
      k_transpose<<<(FIN * FOUT) / 256, 256, 0, stream>>>(W, Wt, flags);
      k_bcount<<<NBLK, 256, 0, stream>>>(edge, E_, chunk, nbuck, C, flags);
      k_bscanA<<<nbuck, 256, 0, stream>>>(C, nbuck, O, btot);
      k_bscanB<<<1, 512, 0, stream>>>(btot, nbuck, bbase, rowptr, N_);
      k_bscatter<<<NBLK, 256, 0, stream>>>(edge, E_, chunk, nbuck, O, bbase, stage, flags);
      k_fine<<<nbuck, 256, 0, stream>>>(stage, bbase, rowptr, csrd, N_);
    }
  }

  k_gemm<<<(N_ + 63) / 64, 256, 0, stream>>>(X, Wt, B, A, H, s1, s2, N_, flags);

  // ---- gather split into 4 row-range dispatches (visibility + same work)
  int rstep = ((N_ + 15) / 16) * 4;        // quarter of rows, multiple of 4
  for (int r0 = 0; r0 < N_; r0 += rstep) {
    int rows = N_ - r0; if (rows > rstep) rows = rstep;
    k_gather<<<(rows + 3) / 4, 256, 0, stream>>>(H, s1, s2, rowptr, csrd,
                                                 d_out, r0, N_, flags);
  }
}

// Round 4
// 761.296 us; speedup vs baseline: 1.3767x; 1.3767x over previous
//
#include <hip/hip_runtime.h>

typedef __bf16 bf16x8 __attribute__((ext_vector_type(8)));
typedef float f32x4 __attribute__((ext_vector_type(4)));
typedef unsigned short u16x8 __attribute__((ext_vector_type(8)));

#define FIN 512
#define FOUT 256
#define NBLK 256          // blocks for bcount/bscatter
#define BSHIFT 8          // bucket = 256 consecutive src nodes

__device__ __forceinline__ float b2f(unsigned short u) {
  union { unsigned int u; float f; } x;
  x.u = ((unsigned int)u) << 16;
  return x.f;
}
__device__ __forceinline__ unsigned short f2b(float f) {
  union { float f; unsigned int u; } x; x.f = f;
  unsigned int u = x.u;
  unsigned int r = (u + 0x7fffu + ((u >> 16) & 1u)) >> 16;
  return (unsigned short)r;
}
// packed f32->bf16 (RNE), 2 values -> 1 dword. gfx950 has no builtin; inline asm.
__device__ __forceinline__ unsigned int cvt_pk_bf16(float lo, float hi) {
  unsigned int r;
  asm("v_cvt_pk_bf16_f32 %0, %1, %2" : "=v"(r) : "v"(lo), "v"(hi));
  return r;
}

// ---- dtype probe: flags[0]=1 iff X is float32; flags[1]=1 iff edge is int64.
__global__ void k_probe(const unsigned short* __restrict__ xh,
                        const int* __restrict__ e, int* __restrict__ flags) {
  __shared__ int cnt[2];
  if (threadIdx.x == 0) { cnt[0] = 0; cnt[1] = 0; }
  __syncthreads();
  int c = 0;
  for (int i = threadIdx.x; i < 32768; i += 256) {
    unsigned short u = xh[i];
    if (((u >> 7) & 0xFF) == 0xFF) c++;
  }
  if (c) atomicAdd(&cnt[0], c);
  if (e[2 * threadIdx.x + 1] == 0) atomicAdd(&cnt[1], 1);
  __syncthreads();
  if (threadIdx.x == 0) {
    flags[0] = (cnt[0] > 0) ? 1 : 0;
    flags[1] = (cnt[1] > 128) ? 1 : 0;
  }
}

// ---- Wt[n*512+k] = bf16(W[k*256+n])
__global__ void k_transpose(const void* __restrict__ W,
                            unsigned short* __restrict__ Wt,
                            const int* __restrict__ flags) {
  int idx = blockIdx.x * 256 + threadIdx.x;
  int k = idx >> 8, n = idx & 255;
  float v = flags[0] ? ((const float*)W)[idx]
                     : b2f(((const unsigned short*)W)[idx]);
  Wt[n * FIN + k] = f2b(v);
}

// ---- H = bf16(X @ W + bias), fused s1 = h@a_src, s2 = h@a_dst.
// BM=64, BN=256, whole-K A-tile in LDS. Launched twice on row ranges
// so its true duration becomes visible in rocprof top-5.
__global__ __launch_bounds__(256) void k_gemm(const void* __restrict__ X,
                                              const unsigned short* __restrict__ Wt,
                                              const void* __restrict__ bias,
                                              const void* __restrict__ A,
                                              unsigned short* __restrict__ H,
                                              float* __restrict__ s1,
                                              float* __restrict__ s2,
                                              int row0, int nrows,
                                              const int* __restrict__ flags) {
  __shared__ char lds[65536];
  const int tid = threadIdx.x;
  const int wave = tid >> 6;
  const int lane = tid & 63;
  const int fm = lane & 15;
  const int fq = lane >> 4;
  const int isf = flags[0];
  const int m0 = row0 + blockIdx.x * 64;

  if (isf) {
#pragma unroll 4
    for (int j = 0; j < 16; ++j) {
      int r = wave * 16 + j;
      int grow = m0 + r; if (grow >= nrows) grow = nrows - 1;
      int c = lane ^ (j & 7);
      const float* gp = (const float*)X + (size_t)grow * FIN + c * 8;
      f32x4 lo = *(const f32x4*)gp;
      f32x4 hi = *(const f32x4*)(gp + 4);
      uint4 pk;
      pk.x = cvt_pk_bf16(lo[0], lo[1]);
      pk.y = cvt_pk_bf16(lo[2], lo[3]);
      pk.z = cvt_pk_bf16(hi[0], hi[1]);
      pk.w = cvt_pk_bf16(hi[2], hi[3]);
      *(uint4*)(lds + r * 1024 + lane * 16) = pk;
    }
  } else {
#pragma unroll
    for (int j = 0; j < 16; ++j) {
      int r = wave * 16 + j;
      int grow = m0 + r; if (grow >= nrows) grow = nrows - 1;
      int c = lane ^ (j & 7);
      const unsigned short* gp = (const unsigned short*)X + (size_t)grow * FIN + c * 8;
      __builtin_amdgcn_global_load_lds(
          (const __attribute__((address_space(1))) void*)gp,
          (__attribute__((address_space(3))) void*)(lds + r * 1024), 16, 0, 0);
    }
  }
  __syncthreads();

  f32x4 acc[4][4];
#pragma unroll
  for (int i = 0; i < 4; i++)
#pragma unroll
    for (int j = 0; j < 4; j++) acc[i][j] = (f32x4){0.f, 0.f, 0.f, 0.f};

  const unsigned short* wp[4];
#pragma unroll
  for (int i = 0; i < 4; i++)
    wp[i] = Wt + (size_t)((wave * 4 + i) * 16 + fm) * FIN + fq * 8;

  const int swz = fm & 7;
  bf16x8 bcur[4];
#pragma unroll
  for (int i = 0; i < 4; i++) bcur[i] = *(const bf16x8*)(wp[i]);

  for (int it = 0; it < 16; ++it) {
    int itn = (it + 1 < 16) ? it + 1 : 15;
    bf16x8 bnext[4];
#pragma unroll
    for (int i = 0; i < 4; i++) bnext[i] = *(const bf16x8*)(wp[i] + itn * 32);
    bf16x8 af[4];
#pragma unroll
    for (int mt = 0; mt < 4; mt++) {
      int slot = (it * 4 + fq) ^ swz;
      af[mt] = *(const bf16x8*)(lds + (mt * 16 + fm) * 1024 + slot * 16);
    }
#pragma unroll
    for (int mt = 0; mt < 4; mt++)
#pragma unroll
      for (int i = 0; i < 4; i++)
        acc[mt][i] = __builtin_amdgcn_mfma_f32_16x16x32_bf16(af[mt], bcur[i], acc[mt][i], 0, 0, 0);
#pragma unroll
    for (int i = 0; i < 4; i++) bcur[i] = bnext[i];
  }

  // ---- epilogue: H store + fused score partials.
  __syncthreads();               // done with A-tile LDS; reuse for score reduce
  float* sc1 = (float*)lds;      // [4 waves][64 rows]
  float* sc2 = sc1 + 256;

  float bvv[4], asv[4], adv[4];
#pragma unroll
  for (int i = 0; i < 4; i++) {
    int col = (wave * 4 + i) * 16 + fm;
    if (isf) {
      bvv[i] = ((const float*)bias)[col];
      asv[i] = ((const float*)A)[col];
      adv[i] = ((const float*)A)[FOUT + col];
    } else {
      bvv[i] = b2f(((const unsigned short*)bias)[col]);
      asv[i] = b2f(((const unsigned short*)A)[col]);
      adv[i] = b2f(((const unsigned short*)A)[FOUT + col]);
    }
  }

#pragma unroll
  for (int mt = 0; mt < 4; mt++) {
#pragma unroll
    for (int r = 0; r < 4; r++) {
      int row = m0 + mt * 16 + fq * 4 + r;
      float p1 = 0.f, p2 = 0.f;
#pragma unroll
      for (int i = 0; i < 4; i++) {
        float h = acc[mt][i][r] + bvv[i];
        if (row < nrows) H[(size_t)row * FOUT + (wave * 4 + i) * 16 + fm] = f2b(h);
        p1 += h * asv[i];
        p2 += h * adv[i];
      }
#pragma unroll
      for (int off = 1; off < 16; off <<= 1) {
        p1 += __shfl_xor(p1, off, 64);
        p2 += __shfl_xor(p2, off, 64);
      }
      if (fm == 0) {
        int rl = mt * 16 + fq * 4 + r;
        sc1[wave * 64 + rl] = p1;
        sc2[wave * 64 + rl] = p2;
      }
    }
  }
  __syncthreads();
  if (tid < 64) {
    int row = m0 + tid;
    if (row < nrows) {
      s1[row] = sc1[tid] + sc1[64 + tid] + sc1[128 + tid] + sc1[192 + tid];
      s2[row] = sc2[tid] + sc2[64 + tid] + sc2[128 + tid] + sc2[192 + tid];
    }
  }
}

// ==== CSR build: 2-level counting sort, no global atomics ====

// per-block bucket histogram -> C[blk*nbuck + b]
__global__ __launch_bounds__(256) void k_bcount(const int* __restrict__ e, int E, int chunk,
                                                int nbuck, int* __restrict__ C,
                                                const int* __restrict__ flags) {
  __shared__ int hist[512];
  int t = threadIdx.x, blk = blockIdx.x;
  for (int i = t; i < nbuck; i += 256) hist[i] = 0;
  __syncthreads();
  int lo = blk * chunk, hi = min(E, lo + chunk);
  bool i64 = flags[1] != 0;
  for (int i = lo + t; i < hi; i += 256) {
    int s = i64 ? ((const int2*)e)[i].x : e[i];
    atomicAdd(&hist[s >> BSHIFT], 1);
  }
  __syncthreads();
  for (int i = t; i < nbuck; i += 256) C[blk * nbuck + i] = hist[i];
}

// per bucket: exclusive scan over the 256 block counts -> O, total -> btot
__global__ __launch_bounds__(256) void k_bscanA(const int* __restrict__ C, int nbuck,
                                                int* __restrict__ O, int* __restrict__ btot) {
  int b = blockIdx.x, t = threadIdx.x;
  int lane = t & 63, w = t >> 6;
  int v = C[t * nbuck + b];
  int x = v;
#pragma unroll
  for (int off = 1; off < 64; off <<= 1) {
    int y = __shfl_up(x, off, 64);
    if (lane >= off) x += y;
  }
  __shared__ int ws[4];
  if (lane == 63) ws[w] = x;
  __syncthreads();
  int wbase = (w > 0 ? ws[0] : 0) + (w > 1 ? ws[1] : 0) + (w > 2 ? ws[2] : 0);
  O[t * nbuck + b] = x + wbase - v;
  if (t == 255) btot[b] = x + wbase;
}

// single block: exclusive scan of bucket totals -> bbase[0..nbuck], rowptr[N]=E
__global__ __launch_bounds__(512) void k_bscanB(const int* __restrict__ btot, int nbuck,
                                                int* __restrict__ bbase,
                                                int* __restrict__ rowptr, int N) {
  __shared__ int sh[512];
  int t = threadIdx.x;
  int v = (t < nbuck) ? btot[t] : 0;
  sh[t] = v;
  __syncthreads();
  for (int off = 1; off < 512; off <<= 1) {
    int u = (t >= off) ? sh[t - off] : 0;
    __syncthreads();
    sh[t] += u;
    __syncthreads();
  }
  if (t < nbuck) bbase[t] = sh[t] - v;
  if (t == nbuck - 1) { bbase[nbuck] = sh[t]; rowptr[N] = sh[t]; }
}

// re-read edges, write packed (slocal<<17)|dst into bucket-grouped stage.
// dst < 131072 (N=100000) and slocal is the 8 src bits below BSHIFT's bucket,
// so one int holds both -> halves stage traffic vs int2.
__global__ __launch_bounds__(256) void k_bscatter(const int* __restrict__ e, int E, int chunk,
                                                  int nbuck, const int* __restrict__ O,
                                                  const int* __restrict__ bbase,
                                                  int* __restrict__ stage,
                                                  const int* __restrict__ flags) {
  __shared__ int cur[512];
  int t = threadIdx.x, blk = blockIdx.x;
  for (int i = t; i < nbuck; i += 256) cur[i] = bbase[i] + O[blk * nbuck + i];
  __syncthreads();
  int lo = blk * chunk, hi = min(E, lo + chunk);
  bool i64 = flags[1] != 0;
  for (int i = lo + t; i < hi; i += 256) {
    int s, d;
    if (i64) { s = ((const int2*)e)[i].x; d = ((const int2*)e)[(size_t)E + i].x; }
    else     { s = e[i];                  d = e[E + i]; }
    int pos = atomicAdd(&cur[s >> BSHIFT], 1);
    stage[pos] = ((s & 255) << 17) | d;
  }
}

// one block per bucket: LDS hist+scan of its 256 nodes -> rowptr slice,
// then LDS-cursor scatter of dst into the bucket's private csrd window.
__global__ __launch_bounds__(256) void k_fine(const int* __restrict__ stage,
                                              const int* __restrict__ bbase,
                                              int* __restrict__ rowptr,
                                              int* __restrict__ csrd, int N) {
  __shared__ int hist[256];
  __shared__ int cursor[256];
  __shared__ int ws[4];
  int b = blockIdx.x, t = threadIdx.x;
  int s0 = b << BSHIFT;
  int base = bbase[b], end = bbase[b + 1], cnt = end - base;
  hist[t] = 0;
  __syncthreads();
  for (int i = t; i < cnt; i += 256) atomicAdd(&hist[stage[base + i] >> 17], 1);
  __syncthreads();
  int v = hist[t];
  int lane = t & 63, w = t >> 6;
  int x = v;
#pragma unroll
  for (int off = 1; off < 64; off <<= 1) {
    int y = __shfl_up(x, off, 64);
    if (lane >= off) x += y;
  }
  if (lane == 63) ws[w] = x;
  __syncthreads();
  int wbase = (w > 0 ? ws[0] : 0) + (w > 1 ? ws[1] : 0) + (w > 2 ? ws[2] : 0);
  int excl = x + wbase - v;
  cursor[t] = base + excl;
  if (s0 + t < N) rowptr[s0 + t] = base + excl;
  __syncthreads();
  for (int i = t; i < cnt; i += 256) {
    int p = stage[base + i];
    int pos = atomicAdd(&cursor[p >> 17], 1);
    csrd[pos] = p & 0x1FFFF;
  }
}

// ---- per-src-node gather. Half-wave pairing; 8 cols/lane.
// Per 64-edge chunk, preload (dst, s2[dst]) into a per-wave LDS buffer, then
// inner loop = {broadcast ds_read_b64 + independent 16B H load + FMA}.
// Launched 4x on row ranges for top-5 visibility (same total work).
__global__ __launch_bounds__(256) void k_gather(const unsigned short* __restrict__ H,
                                                const float* __restrict__ s1,
                                                const float* __restrict__ s2,
                                                const int* __restrict__ rowptr,
                                                const int* __restrict__ csrd,
                                                void* __restrict__ out, int row0, int n,
                                                const int* __restrict__ flags) {
  __shared__ int2 eds[4][64];
  int wave = threadIdx.x >> 6, lane = threadIdx.x & 63;
  int row = row0 + blockIdx.x * 4 + wave;
  if (row >= n) return;
  int half = lane >> 5;
  int hl = lane & 31;
  int beg = rowptr[row], end = rowptr[row + 1];
  float s1v = s1[row];
  const unsigned short* Hb = H + hl * 8;   // per-lane column base; row offset is d*FOUT
  float ac[8];
#pragma unroll
  for (int k = 0; k < 8; k++) ac[k] = 0.f;
  float wsum = 0.f;

  for (int base = beg; base < end; base += 64) {
    int cnt = end - base; if (cnt > 64) cnt = 64;
    int d_pre = 0;
    float s_pre = -1e30f;                  // exp -> 0 for pad slots
    if (lane < cnt) { d_pre = csrd[base + lane]; s_pre = s2[d_pre]; }
    eds[wave][lane] = make_int2(d_pre, __float_as_int(s_pre));  // all 64 lanes write

#pragma unroll 8
    for (int j = 0; j < cnt; j += 2) {
      int jj = j + half;                   // uniform per half-wave -> LDS broadcast
      int2 p = eds[wave][jj];
      int dd = p.x;
      float v = s1v + __int_as_float(p.y);
      v = v > 0.f ? v : 0.2f * v;
      float w = (jj < cnt) ? __expf(v) : 0.f;
      union { u16x8 v; unsigned short u[8]; } hv;
      hv.v = *(const u16x8*)(Hb + (size_t)dd * FOUT);
      wsum += w;
#pragma unroll
      for (int k = 0; k < 8; k++) ac[k] += w * b2f(hv.u[k]);
    }
  }

#pragma unroll
  for (int k = 0; k < 8; k++) ac[k] += __shfl_down(ac[k], 32, 64);
  wsum += __shfl_down(wsum, 32, 64);

  if (half == 0) {
    float inv = 1.f / (wsum + 9e-15f);
    float o[8];
#pragma unroll
    for (int k = 0; k < 8; k++) {
      float x = ac[k] * inv;
      o[k] = x > 0.f ? x : __expf(x) - 1.f;
    }
    if (flags[0]) {
      float* op = (float*)out + (size_t)row * FOUT + hl * 8;
      *(f32x4*)op = (f32x4){o[0], o[1], o[2], o[3]};
      *(f32x4*)(op + 4) = (f32x4){o[4], o[5], o[6], o[7]};
    } else {
      union { u16x8 v; unsigned short u[8]; } ov;
#pragma unroll
      for (int k = 0; k < 8; k++) ov.u[k] = f2b(o[k]);
      *(u16x8*)((unsigned short*)out + (size_t)row * FOUT + hl * 8) = ov.v;
    }
  }
}

extern "C" void kernel_launch(void* const* d_in, const int* in_sizes, int n_in,
                              void* d_out, int out_size, void* d_ws, size_t ws_size,
                              hipStream_t stream) {
  const void* X = d_in[0];
  const int* edge = (const int*)d_in[1];
  const void* W = d_in[2];
  const void* A = d_in[3];
  const void* B = d_in[4];
  int N_ = in_sizes[0] / FIN;     // 100000
  int E_ = in_sizes[1] / 2;       // 3200000
  int nbuck = (N_ + 255) >> BSHIFT;        // 391
  int chunk = (E_ + NBLK - 1) / NBLK;      // 12500

  char* p = (char*)d_ws;
  auto alloc = [&](size_t bytes) {
    char* r = p; p += (bytes + 255) & ~(size_t)255; return r;
  };
  int* flags = (int*)alloc(256);
  unsigned short* H  = (unsigned short*)alloc((size_t)N_ * FOUT * 2);
  unsigned short* Wt = (unsigned short*)alloc((size_t)FIN * FOUT * 2);
  float* s1   = (float*)alloc((size_t)N_ * 4);
  float* s2   = (float*)alloc((size_t)N_ * 4);
  int* rowptr = (int*)alloc((size_t)(N_ + 1) * 4);
  int* csrd   = (int*)alloc((size_t)E_ * 4);
  int* C      = (int*)alloc((size_t)NBLK * nbuck * 4);
  int* O      = (int*)alloc((size_t)NBLK * nbuck * 4);
  int* btot   = (int*)alloc((size_t)nbuck * 4);
  int* bbase  = (int*)alloc((size_t)(nbuck + 1) * 4);
  int* stage  = (int*)alloc((size_t)E_ * 4);

  k_probe<<<1, 256, 0, stream>>>((const unsigned short*)X, edge, flags);
  k_transpose<<<(FIN * FOUT) / 256, 256, 0, stream>>>(W, Wt, flags);

  // ---- gemm split into 2 row-range dispatches (visibility + same work)
  {
    int nblk = (N_ + 63) / 64;             // 1563
    int h1 = (nblk + 1) / 2;               // 782
    int h2 = nblk - h1;                    // 781
    k_gemm<<<h1, 256, 0, stream>>>(X, Wt, B, A, H, s1, s2, 0, N_, flags);
    k_gemm<<<h2, 256, 0, stream>>>(X, Wt, B, A, H, s1, s2, h1 * 64, N_, flags);
  }

  k_bcount<<<NBLK, 256, 0, stream>>>(edge, E_, chunk, nbuck, C, flags);
  k_bscanA<<<nbuck, 256, 0, stream>>>(C, nbuck, O, btot);
  k_bscanB<<<1, 512, 0, stream>>>(btot, nbuck, bbase, rowptr, N_);
  k_bscatter<<<NBLK, 256, 0, stream>>>(edge, E_, chunk, nbuck, O, bbase, stage, flags);
  k_fine<<<nbuck, 256, 0, stream>>>(stage, bbase, rowptr, csrd, N_);

  // ---- gather split into 4 row-range dispatches (visibility + same work)
  int rstep = ((N_ + 15) / 16) * 4;        // quarter of rows, multiple of 4
  for (int r0 = 0; r0 < N_; r0 += rstep) {
    int rows = N_ - r0; if (rows > rstep) rows = rstep;
    k_gather<<<(rows + 3) / 4, 256, 0, stream>>>(H, s1, s2, rowptr, csrd,
                                                 d_out, r0, N_, flags);
  }
}

// Round 5
// 699.009 us; speedup vs baseline: 1.4994x; 1.0891x over previous
//
#include <hip/hip_runtime.h>

typedef __bf16 bf16x8 __attribute__((ext_vector_type(8)));
typedef float f32x4 __attribute__((ext_vector_type(4)));
typedef unsigned short u16x8 __attribute__((ext_vector_type(8)));

#define FIN 512
#define FOUT 256
#define NBLK 256          // blocks for bcount/bscatter
#define BSHIFT 8          // bucket = 256 consecutive src nodes

__device__ __forceinline__ float b2f(unsigned short u) {
  union { unsigned int u; float f; } x;
  x.u = ((unsigned int)u) << 16;
  return x.f;
}
__device__ __forceinline__ unsigned short f2b(float f) {
  union { float f; unsigned int u; } x; x.f = f;
  unsigned int u = x.u;
  unsigned int r = (u + 0x7fffu + ((u >> 16) & 1u)) >> 16;
  return (unsigned short)r;
}
// packed f32->bf16 (RNE), 2 values -> 1 dword. gfx950 has no builtin; inline asm.
__device__ __forceinline__ unsigned int cvt_pk_bf16(float lo, float hi) {
  unsigned int r;
  asm("v_cvt_pk_bf16_f32 %0, %1, %2" : "=v"(r) : "v"(lo), "v"(hi));
  return r;
}

// ---- dtype probe: flags[0]=1 iff X is float32; flags[1]=1 iff edge is int64.
__global__ void k_probe(const unsigned short* __restrict__ xh,
                        const int* __restrict__ e, int* __restrict__ flags) {
  __shared__ int cnt[2];
  if (threadIdx.x == 0) { cnt[0] = 0; cnt[1] = 0; }
  __syncthreads();
  int c = 0;
  for (int i = threadIdx.x; i < 32768; i += 256) {
    unsigned short u = xh[i];
    if (((u >> 7) & 0xFF) == 0xFF) c++;
  }
  if (c) atomicAdd(&cnt[0], c);
  if (e[2 * threadIdx.x + 1] == 0) atomicAdd(&cnt[1], 1);
  __syncthreads();
  if (threadIdx.x == 0) {
    flags[0] = (cnt[0] > 0) ? 1 : 0;
    flags[1] = (cnt[1] > 128) ? 1 : 0;
  }
}

// ---- Wt[n*512+k] = bf16(W[k*256+n])
__global__ void k_transpose(const void* __restrict__ W,
                            unsigned short* __restrict__ Wt,
                            const int* __restrict__ flags) {
  int idx = blockIdx.x * 256 + threadIdx.x;
  int k = idx >> 8, n = idx & 255;
  float v = flags[0] ? ((const float*)W)[idx]
                     : b2f(((const unsigned short*)W)[idx]);
  Wt[n * FIN + k] = f2b(v);
}

// ---- H = bf16(X @ W + bias), fused s1 = h@a_src, s2 = h@a_dst.
// BM=64, BN=256, BK=256 two-pass staging (32 KB LDS -> 3 blocks/CU with
// __launch_bounds__(256,3)), 2-deep Wt register prefetch to cover L2 latency.
// LDS layout per row r (64 rows x 512 B): 32 slots of 16 B; content col-block
// cb stored at slot cb ^ (r&7)  (bank-spread for the MFMA-fragment reads).
__global__ __launch_bounds__(256, 3) void k_gemm(const void* __restrict__ X,
                                                 const unsigned short* __restrict__ Wt,
                                                 const void* __restrict__ bias,
                                                 const void* __restrict__ A,
                                                 unsigned short* __restrict__ H,
                                                 float* __restrict__ s1,
                                                 float* __restrict__ s2,
                                                 int nrows, const int* __restrict__ flags) {
  __shared__ char lds[32768];
  const int tid = threadIdx.x;
  const int wave = tid >> 6;
  const int lane = tid & 63;
  const int fm = lane & 15;
  const int fq = lane >> 4;
  const int hw = lane >> 5;      // half-wave
  const int hl = lane & 31;      // lane within half
  const int isf = flags[0];
  const int m0 = blockIdx.x * 64;

#define STAGE_HALF(h)                                                          \
  do {                                                                         \
    const int k0_ = (h) * 256;                                                 \
    if (isf) {                                                                 \
      _Pragma("unroll")                                                        \
      for (int j = 0; j < 8; ++j) {                                            \
        int r = wave * 16 + j * 2 + hw;                                        \
        int grow = m0 + r; if (grow >= nrows) grow = nrows - 1;                \
        int c = hl ^ (r & 7);                                                  \
        const float* gp = (const float*)X + (size_t)grow * FIN + k0_ + c * 8;  \
        f32x4 lo = *(const f32x4*)gp;                                          \
        f32x4 hi = *(const f32x4*)(gp + 4);                                    \
        uint4 pk;                                                              \
        pk.x = cvt_pk_bf16(lo[0], lo[1]);                                      \
        pk.y = cvt_pk_bf16(lo[2], lo[3]);                                      \
        pk.z = cvt_pk_bf16(hi[0], hi[1]);                                      \
        pk.w = cvt_pk_bf16(hi[2], hi[3]);                                      \
        *(uint4*)(lds + r * 512 + hl * 16) = pk;                               \
      }                                                                        \
    } else {                                                                   \
      _Pragma("unroll")                                                        \
      for (int j = 0; j < 8; ++j) {                                            \
        int r = wave * 16 + j * 2 + hw;                                        \
        int grow = m0 + r; if (grow >= nrows) grow = nrows - 1;                \
        int c = hl ^ (r & 7);                                                  \
        const unsigned short* gp =                                             \
            (const unsigned short*)X + (size_t)grow * FIN + k0_ + c * 8;       \
        __builtin_amdgcn_global_load_lds(                                      \
            (const __attribute__((address_space(1))) void*)gp,                 \
            (__attribute__((address_space(3))) void*)(lds +                    \
                (wave * 16 + j * 2) * 512), 16, 0, 0);                         \
      }                                                                        \
    }                                                                          \
  } while (0)

  f32x4 acc[4][4];
#pragma unroll
  for (int i = 0; i < 4; i++)
#pragma unroll
    for (int j = 0; j < 4; j++) acc[i][j] = (f32x4){0.f, 0.f, 0.f, 0.f};

  const unsigned short* wp[4];
#pragma unroll
  for (int i = 0; i < 4; i++)
    wp[i] = Wt + (size_t)((wave * 4 + i) * 16 + fm) * FIN + fq * 8;

  const int swz = fm & 7;

  STAGE_HALF(0);

  bf16x8 bcur[4], bnxt[4];
#pragma unroll
  for (int i = 0; i < 4; i++) bcur[i] = *(const bf16x8*)(wp[i]);
#pragma unroll
  for (int i = 0; i < 4; i++) bnxt[i] = *(const bf16x8*)(wp[i] + 32);

  __syncthreads();

#define K_BODY(kk, it)                                                         \
  do {                                                                         \
    bf16x8 af[4];                                                              \
    _Pragma("unroll")                                                          \
    for (int mt = 0; mt < 4; mt++) {                                           \
      int slot = ((it) * 4 + fq) ^ swz;                                        \
      af[mt] = *(const bf16x8*)(lds + (mt * 16 + fm) * 512 + slot * 16);       \
    }                                                                          \
    bf16x8 bn[4];                                                              \
    int kn = (kk) + 2; if (kn > 15) kn = 15;                                   \
    _Pragma("unroll")                                                          \
    for (int i = 0; i < 4; i++) bn[i] = *(const bf16x8*)(wp[i] + kn * 32);     \
    _Pragma("unroll")                                                          \
    for (int mt = 0; mt < 4; mt++)                                             \
      _Pragma("unroll")                                                        \
      for (int i = 0; i < 4; i++)                                              \
        acc[mt][i] = __builtin_amdgcn_mfma_f32_16x16x32_bf16(                  \
            af[mt], bcur[i], acc[mt][i], 0, 0, 0);                             \
    _Pragma("unroll")                                                          \
    for (int i = 0; i < 4; i++) { bcur[i] = bnxt[i]; bnxt[i] = bn[i]; }        \
  } while (0)

#pragma unroll
  for (int it = 0; it < 8; ++it) K_BODY(it, it);

  __syncthreads();
  STAGE_HALF(1);
  __syncthreads();

#pragma unroll
  for (int it = 0; it < 8; ++it) K_BODY(8 + it, it);

  // ---- epilogue: H store + fused score partials.
  __syncthreads();               // done with A-tile LDS; reuse for score reduce
  float* sc1 = (float*)lds;      // [4 waves][64 rows]
  float* sc2 = sc1 + 256;

  float bvv[4], asv[4], adv[4];
#pragma unroll
  for (int i = 0; i < 4; i++) {
    int col = (wave * 4 + i) * 16 + fm;
    if (isf) {
      bvv[i] = ((const float*)bias)[col];
      asv[i] = ((const float*)A)[col];
      adv[i] = ((const float*)A)[FOUT + col];
    } else {
      bvv[i] = b2f(((const unsigned short*)bias)[col]);
      asv[i] = b2f(((const unsigned short*)A)[col]);
      adv[i] = b2f(((const unsigned short*)A)[FOUT + col]);
    }
  }

#pragma unroll
  for (int mt = 0; mt < 4; mt++) {
#pragma unroll
    for (int r = 0; r < 4; r++) {
      int row = m0 + mt * 16 + fq * 4 + r;
      float p1 = 0.f, p2 = 0.f;
#pragma unroll
      for (int i = 0; i < 4; i++) {
        float h = acc[mt][i][r] + bvv[i];
        if (row < nrows) H[(size_t)row * FOUT + (wave * 4 + i) * 16 + fm] = f2b(h);
        p1 += h * asv[i];
        p2 += h * adv[i];
      }
#pragma unroll
      for (int off = 1; off < 16; off <<= 1) {
        p1 += __shfl_xor(p1, off, 64);
        p2 += __shfl_xor(p2, off, 64);
      }
      if (fm == 0) {
        int rl = mt * 16 + fq * 4 + r;
        sc1[wave * 64 + rl] = p1;
        sc2[wave * 64 + rl] = p2;
      }
    }
  }
  __syncthreads();
  if (tid < 64) {
    int row = m0 + tid;
    if (row < nrows) {
      s1[row] = sc1[tid] + sc1[64 + tid] + sc1[128 + tid] + sc1[192 + tid];
      s2[row] = sc2[tid] + sc2[64 + tid] + sc2[128 + tid] + sc2[192 + tid];
    }
  }
#undef STAGE_HALF
#undef K_BODY
}

// ==== CSR build: 2-level counting sort, no global atomics ====

// per-block bucket histogram -> C[blk*nbuck + b]
__global__ __launch_bounds__(256) void k_bcount(const int* __restrict__ e, int E, int chunk,
                                                int nbuck, int* __restrict__ C,
                                                const int* __restrict__ flags) {
  __shared__ int hist[512];
  int t = threadIdx.x, blk = blockIdx.x;
  for (int i = t; i < nbuck; i += 256) hist[i] = 0;
  __syncthreads();
  int lo = blk * chunk, hi = min(E, lo + chunk);
  bool i64 = flags[1] != 0;
  for (int i = lo + t; i < hi; i += 256) {
    int s = i64 ? ((const int2*)e)[i].x : e[i];
    atomicAdd(&hist[s >> BSHIFT], 1);
  }
  __syncthreads();
  for (int i = t; i < nbuck; i += 256) C[blk * nbuck + i] = hist[i];
}

// per bucket: exclusive scan over the 256 block counts -> O, total -> btot
__global__ __launch_bounds__(256) void k_bscanA(const int* __restrict__ C, int nbuck,
                                                int* __restrict__ O, int* __restrict__ btot) {
  int b = blockIdx.x, t = threadIdx.x;
  int lane = t & 63, w = t >> 6;
  int v = C[t * nbuck + b];
  int x = v;
#pragma unroll
  for (int off = 1; off < 64; off <<= 1) {
    int y = __shfl_up(x, off, 64);
    if (lane >= off) x += y;
  }
  __shared__ int ws[4];
  if (lane == 63) ws[w] = x;
  __syncthreads();
  int wbase = (w > 0 ? ws[0] : 0) + (w > 1 ? ws[1] : 0) + (w > 2 ? ws[2] : 0);
  O[t * nbuck + b] = x + wbase - v;
  if (t == 255) btot[b] = x + wbase;
}

// single block: exclusive scan of bucket totals -> bbase[0..nbuck], rowptr[N]=E
__global__ __launch_bounds__(512) void k_bscanB(const int* __restrict__ btot, int nbuck,
                                                int* __restrict__ bbase,
                                                int* __restrict__ rowptr, int N) {
  __shared__ int sh[512];
  int t = threadIdx.x;
  int v = (t < nbuck) ? btot[t] : 0;
  sh[t] = v;
  __syncthreads();
  for (int off = 1; off < 512; off <<= 1) {
    int u = (t >= off) ? sh[t - off] : 0;
    __syncthreads();
    sh[t] += u;
    __syncthreads();
  }
  if (t < nbuck) bbase[t] = sh[t] - v;
  if (t == nbuck - 1) { bbase[nbuck] = sh[t]; rowptr[N] = sh[t]; }
}

// re-read edges, write packed (slocal<<17)|dst into bucket-grouped stage.
__global__ __launch_bounds__(256) void k_bscatter(const int* __restrict__ e, int E, int chunk,
                                                  int nbuck, const int* __restrict__ O,
                                                  const int* __restrict__ bbase,
                                                  int* __restrict__ stage,
                                                  const int* __restrict__ flags) {
  __shared__ int cur[512];
  int t = threadIdx.x, blk = blockIdx.x;
  for (int i = t; i < nbuck; i += 256) cur[i] = bbase[i] + O[blk * nbuck + i];
  __syncthreads();
  int lo = blk * chunk, hi = min(E, lo + chunk);
  bool i64 = flags[1] != 0;
  for (int i = lo + t; i < hi; i += 256) {
    int s, d;
    if (i64) { s = ((const int2*)e)[i].x; d = ((const int2*)e)[(size_t)E + i].x; }
    else     { s = e[i];                  d = e[E + i]; }
    int pos = atomicAdd(&cur[s >> BSHIFT], 1);
    stage[pos] = ((s & 255) << 17) | d;
  }
}

// one block per bucket: LDS hist+scan of its 256 nodes -> rowptr slice,
// then LDS-cursor scatter of dst into the bucket's private csrd window.
__global__ __launch_bounds__(256) void k_fine(const int* __restrict__ stage,
                                              const int* __restrict__ bbase,
                                              int* __restrict__ rowptr,
                                              int* __restrict__ csrd, int N) {
  __shared__ int hist[256];
  __shared__ int cursor[256];
  __shared__ int ws[4];
  int b = blockIdx.x, t = threadIdx.x;
  int s0 = b << BSHIFT;
  int base = bbase[b], end = bbase[b + 1], cnt = end - base;
  hist[t] = 0;
  __syncthreads();
  for (int i = t; i < cnt; i += 256) atomicAdd(&hist[stage[base + i] >> 17], 1);
  __syncthreads();
  int v = hist[t];
  int lane = t & 63, w = t >> 6;
  int x = v;
#pragma unroll
  for (int off = 1; off < 64; off <<= 1) {
    int y = __shfl_up(x, off, 64);
    if (lane >= off) x += y;
  }
  if (lane == 63) ws[w] = x;
  __syncthreads();
  int wbase = (w > 0 ? ws[0] : 0) + (w > 1 ? ws[1] : 0) + (w > 2 ? ws[2] : 0);
  int excl = x + wbase - v;
  cursor[t] = base + excl;
  if (s0 + t < N) rowptr[s0 + t] = base + excl;
  __syncthreads();
  for (int i = t; i < cnt; i += 256) {
    int p = stage[base + i];
    int pos = atomicAdd(&cursor[p >> 17], 1);
    csrd[pos] = p & 0x1FFFF;
  }
}

// ---- per-src-node gather. Half-wave pairing; 8 cols/lane.
// Per 64-edge chunk, preload (dst, s2[dst]) into a per-wave LDS buffer, then
// inner loop = {broadcast ds_read_b64 + independent 16B H load + FMA}.
__global__ __launch_bounds__(256) void k_gather(const unsigned short* __restrict__ H,
                                                const float* __restrict__ s1,
                                                const float* __restrict__ s2,
                                                const int* __restrict__ rowptr,
                                                const int* __restrict__ csrd,
                                                void* __restrict__ out, int n,
                                                const int* __restrict__ flags) {
  __shared__ int2 eds[4][64];
  int wave = threadIdx.x >> 6, lane = threadIdx.x & 63;
  int row = blockIdx.x * 4 + wave;
  if (row >= n) return;
  int half = lane >> 5;
  int hl = lane & 31;
  int beg = rowptr[row], end = rowptr[row + 1];
  float s1v = s1[row];
  const unsigned short* Hb = H + hl * 8;   // per-lane column base; row offset is d*FOUT
  float ac[8];
#pragma unroll
  for (int k = 0; k < 8; k++) ac[k] = 0.f;
  float wsum = 0.f;

  for (int base = beg; base < end; base += 64) {
    int cnt = end - base; if (cnt > 64) cnt = 64;
    int d_pre = 0;
    float s_pre = -1e30f;                  // exp -> 0 for pad slots
    if (lane < cnt) { d_pre = csrd[base + lane]; s_pre = s2[d_pre]; }
    eds[wave][lane] = make_int2(d_pre, __float_as_int(s_pre));  // all 64 lanes write

#pragma unroll 8
    for (int j = 0; j < cnt; j += 2) {
      int jj = j + half;                   // uniform per half-wave -> LDS broadcast
      int2 p = eds[wave][jj];
      int dd = p.x;
      float v = s1v + __int_as_float(p.y);
      v = v > 0.f ? v : 0.2f * v;
      float w = (jj < cnt) ? __expf(v) : 0.f;
      union { u16x8 v; unsigned short u[8]; } hv;
      hv.v = *(const u16x8*)(Hb + (size_t)dd * FOUT);
      wsum += w;
#pragma unroll
      for (int k = 0; k < 8; k++) ac[k] += w * b2f(hv.u[k]);
    }
  }

#pragma unroll
  for (int k = 0; k < 8; k++) ac[k] += __shfl_down(ac[k], 32, 64);
  wsum += __shfl_down(wsum, 32, 64);

  if (half == 0) {
    float inv = 1.f / (wsum + 9e-15f);
    float o[8];
#pragma unroll
    for (int k = 0; k < 8; k++) {
      float x = ac[k] * inv;
      o[k] = x > 0.f ? x : __expf(x) - 1.f;
    }
    if (flags[0]) {
      float* op = (float*)out + (size_t)row * FOUT + hl * 8;
      *(f32x4*)op = (f32x4){o[0], o[1], o[2], o[3]};
      *(f32x4*)(op + 4) = (f32x4){o[4], o[5], o[6], o[7]};
    } else {
      union { u16x8 v; unsigned short u[8]; } ov;
#pragma unroll
      for (int k = 0; k < 8; k++) ov.u[k] = f2b(o[k]);
      *(u16x8*)((unsigned short*)out + (size_t)row * FOUT + hl * 8) = ov.v;
    }
  }
}

extern "C" void kernel_launch(void* const* d_in, const int* in_sizes, int n_in,
                              void* d_out, int out_size, void* d_ws, size_t ws_size,
                              hipStream_t stream) {
  const void* X = d_in[0];
  const int* edge = (const int*)d_in[1];
  const void* W = d_in[2];
  const void* A = d_in[3];
  const void* B = d_in[4];
  int N_ = in_sizes[0] / FIN;     // 100000
  int E_ = in_sizes[1] / 2;       // 3200000
  int nbuck = (N_ + 255) >> BSHIFT;        // 391
  int chunk = (E_ + NBLK - 1) / NBLK;      // 12500

  char* p = (char*)d_ws;
  auto alloc = [&](size_t bytes) {
    char* r = p; p += (bytes + 255) & ~(size_t)255; return r;
  };
  int* flags = (int*)alloc(256);
  unsigned short* H  = (unsigned short*)alloc((size_t)N_ * FOUT * 2);
  unsigned short* Wt = (unsigned short*)alloc((size_t)FIN * FOUT * 2);
  float* s1   = (float*)alloc((size_t)N_ * 4);
  float* s2   = (float*)alloc((size_t)N_ * 4);
  int* rowptr = (int*)alloc((size_t)(N_ + 1) * 4);
  int* csrd   = (int*)alloc((size_t)E_ * 4);
  int* C      = (int*)alloc((size_t)NBLK * nbuck * 4);
  int* O      = (int*)alloc((size_t)NBLK * nbuck * 4);
  int* btot   = (int*)alloc((size_t)nbuck * 4);
  int* bbase  = (int*)alloc((size_t)(nbuck + 1) * 4);
  int* stage  = (int*)alloc((size_t)E_ * 4);

  k_probe<<<1, 256, 0, stream>>>((const unsigned short*)X, edge, flags);
  k_transpose<<<(FIN * FOUT) / 256, 256, 0, stream>>>(W, Wt, flags);
  k_gemm<<<(N_ + 63) / 64, 256, 0, stream>>>(X, Wt, B, A, H, s1, s2, N_, flags);
  k_bcount<<<NBLK, 256, 0, stream>>>(edge, E_, chunk, nbuck, C, flags);
  k_bscanA<<<nbuck, 256, 0, stream>>>(C, nbuck, O, btot);
  k_bscanB<<<1, 512, 0, stream>>>(btot, nbuck, bbase, rowptr, N_);
  k_bscatter<<<NBLK, 256, 0, stream>>>(edge, E_, chunk, nbuck, O, bbase, stage, flags);
  k_fine<<<nbuck, 256, 0, stream>>>(stage, bbase, rowptr, csrd, N_);
  k_gather<<<(N_ + 3) / 4, 256, 0, stream>>>(H, s1, s2, rowptr, csrd,
                                             d_out, N_, flags);
}